// Round 18
// baseline (59.552 us; speedup 1.0000x reference)
//
#include <hip/hip_runtime.h>
#include <hip/hip_bf16.h>

typedef __attribute__((ext_vector_type(8))) short    s8v;  // bf16x8 MFMA operand
typedef __attribute__((ext_vector_type(4))) float    f4v;  // fp32x4 MFMA C/D
typedef __attribute__((ext_vector_type(4))) unsigned u4v;

#define PIN(x) asm volatile("" : "+v"(x))

__device__ __forceinline__ unsigned short bfu(float x){
  union { __hip_bfloat16 h; unsigned short u; } cv;
  cv.h = __float2bfloat16(x);
  return cv.u;
}
__device__ __forceinline__ unsigned pkbf(float lo, float hi){
  return (unsigned)bfu(lo) | ((unsigned)bfu(hi) << 16);
}
__device__ __forceinline__ s8v mkfrag(unsigned a, unsigned b, unsigned c_, unsigned d){
  u4v u = {a, b, c_, d};
  return __builtin_bit_cast(s8v, u);
}
__device__ __forceinline__ f4v MM(s8v a, s8v b, f4v acc){
  return __builtin_amdgcn_mfma_f32_16x16x32_bf16(a, b, acc, 0, 0, 0);
}

// Packed D-quad: p0 = (row 4g, 4g+1), p1 = (row 4g+2, 4g+3) at col c.
struct Pk { unsigned p0, p1; };
template<bool RELU>
__device__ __forceinline__ Pk mkpk(f4v d){
  float a = d[0], b = d[1], c_ = d[2], e = d[3];
  if (RELU){ a = fmaxf(a,0.f); b = fmaxf(b,0.f); c_ = fmaxf(c_,0.f); e = fmaxf(e,0.f); }
  Pk r; r.p0 = pkbf(a, b); r.p1 = pkbf(c_, e); return r;
}

// ZERO-SHUFFLE CHAINING (verified R5).  R10 lesson: keep g==0 input masks.
// R13/R14/R15 lesson: this EXACT structure (loop+PIN, wave0 packing) is the
// verified-correct one; flat rewrite & sched_barrier variants miscompile.
__device__ __forceinline__ s8v bfragK16(Pk x){ return mkfrag(x.p0, x.p1, 0u, 0u); }
__device__ __forceinline__ s8v bfragCat(Pk x, Pk y){ return mkfrag(x.p0, x.p1, y.p0, y.p1); }

__device__ __forceinline__ s8v loadA16(const float* __restrict__ W, int K, int c, int g,
                                       float scale = 1.0f){
  int r0 = 4*g;
  unsigned u0 = pkbf(r0+0<K ? W[(r0+0)*16+c]*scale : 0.f, r0+1<K ? W[(r0+1)*16+c]*scale : 0.f);
  unsigned u1 = pkbf(r0+2<K ? W[(r0+2)*16+c]*scale : 0.f, r0+3<K ? W[(r0+3)*16+c]*scale : 0.f);
  return mkfrag(u0, u1, 0u, 0u);
}
__device__ __forceinline__ s8v loadA32(const float* __restrict__ W, int c, int g){
  int r0 = 4*g;
  unsigned u0 = pkbf(W[(r0+0)*16+c],      W[(r0+1)*16+c]);
  unsigned u1 = pkbf(W[(r0+2)*16+c],      W[(r0+3)*16+c]);
  unsigned u2 = pkbf(W[(16+r0+0)*16+c],   W[(16+r0+1)*16+c]);
  unsigned u3 = pkbf(W[(16+r0+2)*16+c],   W[(16+r0+3)*16+c]);
  return mkfrag(u0, u1, u2, u3);
}

__device__ __forceinline__ void pl32(unsigned &a, unsigned &b){
  asm("v_permlane32_swap_b32 %0, %1" : "+v"(a), "+v"(b));
}
__device__ __forceinline__ void pl16(unsigned &a, unsigned &b){
  asm("v_permlane16_swap_b32 %0, %1" : "+v"(a), "+v"(b));
}
__device__ __forceinline__ float qsum(float part){
  unsigned pu = __builtin_bit_cast(unsigned, part), pv = pu;
  pl16(pu, pv);
  part = __builtin_bit_cast(float, pu) + __builtin_bit_cast(float, pv);
  pu = __builtin_bit_cast(unsigned, part); pv = pu;
  pl32(pu, pv);
  return __builtin_bit_cast(float, pu) + __builtin_bit_cast(float, pv);
}

// ---- LDS weight cache layout (R9..R12 structure, proven correct) ----
#define R16B  (11*512)          // 8B-fragment region: 11 frags x 64 lanes x 8B
#define RBB   (R16B + 4*1024)   // 16B-fragment region: 4 frags x 64 lanes x 16B
#define LDSZ  (RBB + 14*64)     // bias region: 14 vectors x 16 floats

__global__ void __launch_bounds__(256, 2) egnn_ilp4(
    const float* __restrict__ nf,   const float* __restrict__ dist,
    const float* __restrict__ dz,   const float* __restrict__ s2p,
    const float* __restrict__ neW1, const float* __restrict__ neb1,
    const float* __restrict__ neW2, const float* __restrict__ neb2,
    const float* __restrict__ eeW1, const float* __restrict__ eeb1,
    const float* __restrict__ eeW2, const float* __restrict__ eeb2,
    const float* __restrict__ msgW1, const float* __restrict__ msgb1,
    const float* __restrict__ msgW2, const float* __restrict__ msgb2,
    const float* __restrict__ updW1, const float* __restrict__ updb1,
    const float* __restrict__ updW2, const float* __restrict__ updb2,
    const float* __restrict__ clsW1, const float* __restrict__ clsb1,
    const float* __restrict__ clsW2, const float* __restrict__ clsb2,
    float* __restrict__ out, int B, int niters, int nwaves)
{
  __shared__ __align__(16) char wl[LDSZ];
  const int tid  = threadIdx.x;
  const int lane = tid & 63;
  const int c = lane & 15;
  const int g = lane >> 4;

  // ---- one-time per-block weight packing into LDS (wave 0 only) ----
  if (tid < 64){
    auto st8 = [&](int j, s8v f){
      u4v u = __builtin_bit_cast(u4v, f);
      *reinterpret_cast<uint2*>(wl + j*512 + lane*8) = make_uint2(u[0], u[1]);
    };
    auto st16 = [&](int j, s8v f){
      *reinterpret_cast<u4v*>(wl + R16B + j*1024 + lane*16) = __builtin_bit_cast(u4v, f);
    };
    st8(0, loadA16(neW1,  2, c, g));
    st8(1, loadA16(neW2, 16, c, g));
    st8(2, loadA16(eeW1,  3, c, g));
    st8(3, loadA16(eeW2, 16, c, g));
    st8(4, loadA16(clsW1,16, c, g, 0.5f));       // fold node-mean 0.5
    #pragma unroll
    for (int l = 0; l < 2; ++l){
      st8(5+l,  loadA16(msgW1 + l*768 + 512, 16, c, g));  // ee rows 32..47
      st8(7+l,  loadA16(msgW2 + l*256, 16, c, g));
      st8(9+l,  loadA16(updW2 + l*256, 16, c, g));
      st16(l,   loadA32(msgW1 + l*768, c, g));            // concat rows 0..31
      st16(2+l, loadA32(updW1 + l*512, c, g));            // h rows, msg rows
    }
    if (lane < 16){
      float* bf = reinterpret_cast<float*>(wl + RBB);
      bf[ 0*16+lane] = neb1[lane];      bf[ 1*16+lane] = neb2[lane];
      bf[ 2*16+lane] = eeb1[lane];      bf[ 3*16+lane] = eeb2[lane];
      bf[ 4*16+lane] = clsb1[lane];
      bf[ 5*16+lane] = msgb1[lane];     bf[ 6*16+lane] = msgb1[16+lane];
      bf[ 7*16+lane] = msgb2[lane];     bf[ 8*16+lane] = msgb2[16+lane];
      bf[ 9*16+lane] = updb1[lane];     bf[10*16+lane] = updb1[16+lane];
      bf[11*16+lane] = updb2[lane];     bf[12*16+lane] = updb2[16+lane];
      bf[13*16+lane] = clsW2[lane];
    }
  }
  __syncthreads();

  const float cb2 = clsb2[0];          // wave-uniform -> SGPR
  const int gwave = blockIdx.x * 4 + (tid >> 6);

  int it = gwave;
  float4 nfe[4]; float di[4], zz[4], sp[4];
  #pragma unroll
  for (int q = 0; q < 4; ++q){ nfe[q] = make_float4(0,0,0,0); di[q]=zz[q]=sp[q]=0.f; }
  if (it < niters){
    #pragma unroll
    for (int q = 0; q < 4; ++q){
      int e = min((4*it + q)*16 + c, B-1);
      nfe[q] = *reinterpret_cast<const float4*>(nf + (size_t)e * 4);
      di[q] = dist[e]; zz[q] = dz[e]; sp[q] = s2p[e];
    }
  }

  #pragma unroll 1
  for (; it < niters; it += nwaves){
    // PINned offsets: keep the weight/bias ds_reads in-loop (R8 spill trap).
    int o8 = lane*8, o16 = lane*16, ob = g*16;
    PIN(o8); PIN(o16); PIN(ob);
    const char* w8  = wl + o8;
    const char* w16 = wl + R16B + o16;
    const char* wb  = wl + RBB + ob;
    auto ld8 = [&](int j){
      uint2 v = *reinterpret_cast<const uint2*>(w8 + j*512);
      return mkfrag(v.x, v.y, 0u, 0u);
    };
    auto ld16 = [&](int j){
      return __builtin_bit_cast(s8v, *reinterpret_cast<const u4v*>(w16 + j*1024));
    };
    auto ldc = [&](int j){
      return *reinterpret_cast<const f4v*>(wb + j*64);
    };

    // prefetch next iteration's inputs
    float4 nfeN[4]; float diN[4], zzN[4], spN[4];
    #pragma unroll
    for (int q = 0; q < 4; ++q){ nfeN[q] = nfe[q]; diN[q]=di[q]; zzN[q]=zz[q]; spN[q]=sp[q]; }
    const int nit = it + nwaves;
    if (nit < niters){
      #pragma unroll
      for (int q = 0; q < 4; ++q){
        int e = min((4*nit + q)*16 + c, B-1);
        nfeN[q] = *reinterpret_cast<const float4*>(nf + (size_t)e * 4);
        diN[q] = dist[e]; zzN[q] = dz[e]; spN[q] = s2p[e];
      }
    }

    // ---- input fragments (g==0 masks REQUIRED — R10 lesson) ----
    s8v b0f[4], b1f[4], bef[4];
    #pragma unroll
    for (int q = 0; q < 4; ++q){
      b0f[q] = mkfrag(g==0 ? pkbf(nfe[q].x, nfe[q].y) : 0u, 0u, 0u, 0u);
      b1f[q] = mkfrag(g==0 ? pkbf(nfe[q].z, nfe[q].w) : 0u, 0u, 0u, 0u);
      bef[q] = mkfrag(g==0 ? pkbf(di[q], zz[q]) : 0u, g==0 ? pkbf(sp[q], 0.f) : 0u, 0u, 0u);
    }

    // ---- embeddings ----
    f4v t0[4], t1[4], te[4], h0[4], h1[4], ee[4];
    { s8v A = ld8(0); f4v C = ldc(0);
      #pragma unroll
      for (int q = 0; q < 4; ++q){ t0[q] = MM(A, b0f[q], C); t1[q] = MM(A, b1f[q], C); } }
    { s8v A = ld8(2); f4v C = ldc(2);
      #pragma unroll
      for (int q = 0; q < 4; ++q){ te[q] = MM(A, bef[q], C); } }
    { s8v A = ld8(1); f4v C = ldc(1);
      #pragma unroll
      for (int q = 0; q < 4; ++q){
        h0[q] = MM(A, bfragK16(mkpk<true>(t0[q])), C);
        h1[q] = MM(A, bfragK16(mkpk<true>(t1[q])), C); } }
    Pk eeP[4];
    { s8v A = ld8(3); f4v C = ldc(3);
      #pragma unroll
      for (int q = 0; q < 4; ++q){ ee[q] = MM(A, bfragK16(mkpk<true>(te[q])), C); } }
    #pragma unroll
    for (int q = 0; q < 4; ++q){ eeP[q] = mkpk<false>(ee[q]); }

    // ---- eC HOIST (R17): both layers' ee-contribution depends only on eeP,
    //      not on h — off each layer's h-dependent critical chain.
    //      Rounding-identical to R12 (same operands, same per-value order).
    f4v eC[2][4];
    #pragma unroll
    for (int l = 0; l < 2; ++l){
      s8v A = ld8(5+l); f4v C = ldc(5+l);
      #pragma unroll
      for (int q = 0; q < 4; ++q){ eC[l][q] = MM(A, bfragK16(eeP[q]), C); }
    }

    // ---- message-passing layers ----
    #pragma unroll
    for (int l = 0; l < 2; ++l){
      Pk ph0[4], ph1[4];
      #pragma unroll
      for (int q = 0; q < 4; ++q){ ph0[q] = mkpk<false>(h0[q]); ph1[q] = mkpk<false>(h1[q]); }
      f4v m0[4], m1[4];
      { s8v A = ld16(l);
        #pragma unroll
        for (int q = 0; q < 4; ++q){
          m0[q] = MM(A, bfragCat(ph0[q], ph1[q]), eC[l][q]);
          m1[q] = MM(A, bfragCat(ph1[q], ph0[q]), eC[l][q]); } }
      f4v g0[4], g1[4];
      { s8v A = ld8(7+l); f4v C = ldc(7+l);
        #pragma unroll
        for (int q = 0; q < 4; ++q){
          g0[q] = MM(A, bfragK16(mkpk<true>(m0[q])), C);
          g1[q] = MM(A, bfragK16(mkpk<true>(m1[q])), C); } }
      f4v u0[4], u1[4];
      { s8v A = ld16(2+l); f4v C = ldc(9+l);
        #pragma unroll
        for (int q = 0; q < 4; ++q){
          u0[q] = MM(A, bfragCat(ph0[q], mkpk<false>(g0[q])), C);
          u1[q] = MM(A, bfragCat(ph1[q], mkpk<false>(g1[q])), C); } }
      { s8v A = ld8(9+l); f4v C = ldc(11+l);
        #pragma unroll
        for (int q = 0; q < 4; ++q){
          h0[q] = h0[q] + MM(A, bfragK16(mkpk<true>(u0[q])), C);
          h1[q] = h1[q] + MM(A, bfragK16(mkpk<true>(u1[q])), C); } }
    }

    // ---- classifier (0.5 pre-folded into the aCl fragment) ----
    { s8v A = ld8(4); f4v C = ldc(4); f4v w2v = ldc(13);
      #pragma unroll
      for (int q = 0; q < 4; ++q){
        f4v tc = MM(A, bfragK16(mkpk<false>(h0[q] + h1[q])), C);
        float part = fmaxf(tc[0],0.f)*w2v[0] + fmaxf(tc[1],0.f)*w2v[1]
                   + fmaxf(tc[2],0.f)*w2v[2] + fmaxf(tc[3],0.f)*w2v[3];
        part = qsum(part);
        int e = (4*it + q)*16 + c;
        if (lane < 16 && e < B) out[e] = part + cb2;
      } }

    #pragma unroll
    for (int q = 0; q < 4; ++q){ nfe[q] = nfeN[q]; di[q]=diN[q]; zz[q]=zzN[q]; sp[q]=spN[q]; }
  }
}

extern "C" void kernel_launch(void* const* d_in, const int* in_sizes, int n_in,
                              void* d_out, int out_size, void* d_ws, size_t ws_size,
                              hipStream_t stream) {
  const float* nf    = (const float*)d_in[0];
  const float* dist  = (const float*)d_in[1];
  const float* dz    = (const float*)d_in[2];
  const float* s2p   = (const float*)d_in[3];
  const float* neW1  = (const float*)d_in[4];
  const float* neb1  = (const float*)d_in[5];
  const float* neW2  = (const float*)d_in[6];
  const float* neb2  = (const float*)d_in[7];
  const float* eeW1  = (const float*)d_in[8];
  const float* eeb1  = (const float*)d_in[9];
  const float* eeW2  = (const float*)d_in[10];
  const float* eeb2  = (const float*)d_in[11];
  const float* msgW1 = (const float*)d_in[12];
  const float* msgb1 = (const float*)d_in[13];
  const float* msgW2 = (const float*)d_in[14];
  const float* msgb2 = (const float*)d_in[15];
  const float* updW1 = (const float*)d_in[16];
  const float* updb1 = (const float*)d_in[17];
  const float* updW2 = (const float*)d_in[18];
  const float* updb2 = (const float*)d_in[19];
  const float* clsW1 = (const float*)d_in[20];
  const float* clsb1 = (const float*)d_in[21];
  const float* clsW2 = (const float*)d_in[22];
  const float* clsb2 = (const float*)d_in[23];

  const int B = in_sizes[1];
  const int ngroups = (B + 15) / 16;
  const int niters  = (ngroups + 3) / 4;       // 4 groups per wave-iteration
  // R18: R17 code + 2048 blocks (8 blocks/CU queued -> tail load-balance,
  // 2 iters/wave).  A/B square: vs R17 only blocks changed; vs R12 only
  // the eC hoist changed.
  int blocks = 2048;
  if (blocks * 4 > niters) blocks = (niters + 3) / 4;
  const int nwaves = blocks * 4;

  egnn_ilp4<<<blocks, 256, 0, stream>>>(
      nf, dist, dz, s2p,
      neW1, neb1, neW2, neb2,
      eeW1, eeb1, eeW2, eeb2,
      msgW1, msgb1, msgW2, msgb2,
      updW1, updb1, updW2, updb2,
      clsW1, clsb1, clsW2, clsb2,
      (float*)d_out, B, niters, nwaves);
}

// Round 19
// 51.842 us; speedup vs baseline: 1.1487x; 1.1487x over previous
//
#include <hip/hip_runtime.h>
#include <hip/hip_bf16.h>

typedef __attribute__((ext_vector_type(8))) short    s8v;  // bf16x8 (packing only)
typedef __attribute__((ext_vector_type(4))) short    s4v;  // bf16x4 MFMA-16 operand (2 VGPRs)
typedef __attribute__((ext_vector_type(4))) float    f4v;  // fp32x4 MFMA C/D
typedef __attribute__((ext_vector_type(4))) unsigned u4v;
typedef __attribute__((ext_vector_type(2))) unsigned u2v;

#define PIN(x) asm volatile("" : "+v"(x))

__device__ __forceinline__ unsigned short bfu(float x){
  union { __hip_bfloat16 h; unsigned short u; } cv;
  cv.h = __float2bfloat16(x);
  return cv.u;
}
__device__ __forceinline__ unsigned pkbf(float lo, float hi){
  return (unsigned)bfu(lo) | ((unsigned)bfu(hi) << 16);
}
__device__ __forceinline__ s8v mkfrag(unsigned a, unsigned b, unsigned c_, unsigned d){
  u4v u = {a, b, c_, d};
  return __builtin_bit_cast(s8v, u);
}
// 16x16x16 bf16 MFMA: 2-reg A/B — the packed D-quad (p0,p1) IS the B operand
// (reg j at lane(g,c) covers k=4g+2j..+1 -> feature f=4g+r sits at k=4g+r,
// identity mapping; A[c][k]=W[k][c] with NO row permutation).
__device__ __forceinline__ f4v MM16(s4v a, s4v b, f4v acc){
  return __builtin_amdgcn_mfma_f32_16x16x16bf16_1k(a, b, acc, 0, 0, 0);
}

// Packed D-quad: p0 = (row 4g, 4g+1), p1 = (row 4g+2, 4g+3) at col c.
struct Pk { unsigned p0, p1; };
template<bool RELU>
__device__ __forceinline__ Pk mkpk(f4v d){
  float a = d[0], b = d[1], c_ = d[2], e = d[3];
  if (RELU){ a = fmaxf(a,0.f); b = fmaxf(b,0.f); c_ = fmaxf(c_,0.f); e = fmaxf(e,0.f); }
  Pk r; r.p0 = pkbf(a, b); r.p1 = pkbf(c_, e); return r;
}
__device__ __forceinline__ s4v pk2b(Pk x){
  u2v u = {x.p0, x.p1};
  return __builtin_bit_cast(s4v, u);          // free: D-quad -> B operand
}
__device__ __forceinline__ s4v mk2(unsigned a, unsigned b){
  u2v u = {a, b};
  return __builtin_bit_cast(s4v, u);
}

// LDS packing content IDENTICAL to R12/R17 (proven): loadA16 stores
// (u0,u1) = W rows 4g..4g+3 packed -> exactly the MM16 A-operand.
// loadA32 stores (u0,u1,u2,u3); (u0,u1) = lo-half rows, (u2,u3) = hi-half.
__device__ __forceinline__ s8v loadA16(const float* __restrict__ W, int K, int c, int g,
                                       float scale = 1.0f){
  int r0 = 4*g;
  unsigned u0 = pkbf(r0+0<K ? W[(r0+0)*16+c]*scale : 0.f, r0+1<K ? W[(r0+1)*16+c]*scale : 0.f);
  unsigned u1 = pkbf(r0+2<K ? W[(r0+2)*16+c]*scale : 0.f, r0+3<K ? W[(r0+3)*16+c]*scale : 0.f);
  return mkfrag(u0, u1, 0u, 0u);
}
__device__ __forceinline__ s8v loadA32(const float* __restrict__ W, int c, int g){
  int r0 = 4*g;
  unsigned u0 = pkbf(W[(r0+0)*16+c],      W[(r0+1)*16+c]);
  unsigned u1 = pkbf(W[(r0+2)*16+c],      W[(r0+3)*16+c]);
  unsigned u2 = pkbf(W[(16+r0+0)*16+c],   W[(16+r0+1)*16+c]);
  unsigned u3 = pkbf(W[(16+r0+2)*16+c],   W[(16+r0+3)*16+c]);
  return mkfrag(u0, u1, u2, u3);
}

__device__ __forceinline__ void pl32(unsigned &a, unsigned &b){
  asm("v_permlane32_swap_b32 %0, %1" : "+v"(a), "+v"(b));
}
__device__ __forceinline__ void pl16(unsigned &a, unsigned &b){
  asm("v_permlane16_swap_b32 %0, %1" : "+v"(a), "+v"(b));
}
__device__ __forceinline__ float qsum(float part){
  unsigned pu = __builtin_bit_cast(unsigned, part), pv = pu;
  pl16(pu, pv);
  part = __builtin_bit_cast(float, pu) + __builtin_bit_cast(float, pv);
  pu = __builtin_bit_cast(unsigned, part); pv = pu;
  pl32(pu, pv);
  return __builtin_bit_cast(float, pu) + __builtin_bit_cast(float, pv);
}

// ---- LDS weight cache layout (bytes identical to R12/R17) ----
#define R16B  (11*512)          // 8B-fragment region: 11 frags x 64 lanes x 8B
#define RBB   (R16B + 4*1024)   // 16B-fragment region: 4 frags x 64 lanes x 16B
#define LDSZ  (RBB + 14*64)     // bias region: 14 vectors x 16 floats

__global__ void __launch_bounds__(256, 2) egnn_m16(
    const float* __restrict__ nf,   const float* __restrict__ dist,
    const float* __restrict__ dz,   const float* __restrict__ s2p,
    const float* __restrict__ neW1, const float* __restrict__ neb1,
    const float* __restrict__ neW2, const float* __restrict__ neb2,
    const float* __restrict__ eeW1, const float* __restrict__ eeb1,
    const float* __restrict__ eeW2, const float* __restrict__ eeb2,
    const float* __restrict__ msgW1, const float* __restrict__ msgb1,
    const float* __restrict__ msgW2, const float* __restrict__ msgb2,
    const float* __restrict__ updW1, const float* __restrict__ updb1,
    const float* __restrict__ updW2, const float* __restrict__ updb2,
    const float* __restrict__ clsW1, const float* __restrict__ clsb1,
    const float* __restrict__ clsW2, const float* __restrict__ clsb2,
    float* __restrict__ out, int B, int niters, int nwaves)
{
  __shared__ __align__(16) char wl[LDSZ];
  const int tid  = threadIdx.x;
  const int lane = tid & 63;
  const int c = lane & 15;
  const int g = lane >> 4;

  // ---- one-time per-block weight packing into LDS (wave 0 only) ----
  if (tid < 64){
    auto st8 = [&](int j, s8v f){
      u4v u = __builtin_bit_cast(u4v, f);
      *reinterpret_cast<uint2*>(wl + j*512 + lane*8) = make_uint2(u[0], u[1]);
    };
    auto st16 = [&](int j, s8v f){
      *reinterpret_cast<u4v*>(wl + R16B + j*1024 + lane*16) = __builtin_bit_cast(u4v, f);
    };
    st8(0, loadA16(neW1,  2, c, g));
    st8(1, loadA16(neW2, 16, c, g));
    st8(2, loadA16(eeW1,  3, c, g));
    st8(3, loadA16(eeW2, 16, c, g));
    st8(4, loadA16(clsW1,16, c, g, 0.5f));       // fold node-mean 0.5
    #pragma unroll
    for (int l = 0; l < 2; ++l){
      st8(5+l,  loadA16(msgW1 + l*768 + 512, 16, c, g));  // ee rows 32..47
      st8(7+l,  loadA16(msgW2 + l*256, 16, c, g));
      st8(9+l,  loadA16(updW2 + l*256, 16, c, g));
      st16(l,   loadA32(msgW1 + l*768, c, g));            // concat rows 0..31
      st16(2+l, loadA32(updW1 + l*512, c, g));            // h rows, msg rows
    }
    if (lane < 16){
      float* bf = reinterpret_cast<float*>(wl + RBB);
      bf[ 0*16+lane] = neb1[lane];      bf[ 1*16+lane] = neb2[lane];
      bf[ 2*16+lane] = eeb1[lane];      bf[ 3*16+lane] = eeb2[lane];
      bf[ 4*16+lane] = clsb1[lane];
      bf[ 5*16+lane] = msgb1[lane];     bf[ 6*16+lane] = msgb1[16+lane];
      bf[ 7*16+lane] = msgb2[lane];     bf[ 8*16+lane] = msgb2[16+lane];
      bf[ 9*16+lane] = updb1[lane];     bf[10*16+lane] = updb1[16+lane];
      bf[11*16+lane] = updb2[lane];     bf[12*16+lane] = updb2[16+lane];
      bf[13*16+lane] = clsW2[lane];
    }
  }
  __syncthreads();

  const float cb2 = clsb2[0];          // wave-uniform -> SGPR
  const int gwave = blockIdx.x * 4 + (tid >> 6);

  int it = gwave;
  float4 nfe[4]; float di[4], zz[4], sp[4];
  #pragma unroll
  for (int q = 0; q < 4; ++q){ nfe[q] = make_float4(0,0,0,0); di[q]=zz[q]=sp[q]=0.f; }
  if (it < niters){
    #pragma unroll
    for (int q = 0; q < 4; ++q){
      int e = min((4*it + q)*16 + c, B-1);
      nfe[q] = *reinterpret_cast<const float4*>(nf + (size_t)e * 4);
      di[q] = dist[e]; zz[q] = dz[e]; sp[q] = s2p[e];
    }
  }

  #pragma unroll 1
  for (; it < niters; it += nwaves){
    // PINned offsets: keep the weight/bias ds_reads in-loop (R8 spill trap).
    int o8 = lane*8, o16 = lane*16, ob = g*16;
    PIN(o8); PIN(o16); PIN(ob);
    const char* w8  = wl + o8;
    const char* w16 = wl + R16B + o16;
    const char* wb  = wl + RBB + ob;
    auto ld8 = [&](int j){                    // 2-reg A operand, direct
      uint2 v = *reinterpret_cast<const uint2*>(w8 + j*512);
      return mk2(v.x, v.y);
    };
    struct A32 { s4v lo, hi; };
    auto ld16 = [&](int j){                   // K=32 A: lo/hi 2-reg halves
      u4v v = *reinterpret_cast<const u4v*>(w16 + j*1024);
      A32 r; r.lo = mk2(v[0], v[1]); r.hi = mk2(v[2], v[3]);
      return r;
    };
    auto ldc = [&](int j){
      return *reinterpret_cast<const f4v*>(wb + j*64);
    };

    // prefetch next iteration's inputs
    float4 nfeN[4]; float diN[4], zzN[4], spN[4];
    #pragma unroll
    for (int q = 0; q < 4; ++q){ nfeN[q] = nfe[q]; diN[q]=di[q]; zzN[q]=zz[q]; spN[q]=sp[q]; }
    const int nit = it + nwaves;
    if (nit < niters){
      #pragma unroll
      for (int q = 0; q < 4; ++q){
        int e = min((4*nit + q)*16 + c, B-1);
        nfeN[q] = *reinterpret_cast<const float4*>(nf + (size_t)e * 4);
        diN[q] = dist[e]; zzN[q] = dz[e]; spN[q] = s2p[e];
      }
    }

    // ---- input fragments (g==0 masks REQUIRED — R10 lesson) ----
    s4v b0f[4], b1f[4], bef[4];
    #pragma unroll
    for (int q = 0; q < 4; ++q){
      b0f[q] = mk2(g==0 ? pkbf(nfe[q].x, nfe[q].y) : 0u, 0u);
      b1f[q] = mk2(g==0 ? pkbf(nfe[q].z, nfe[q].w) : 0u, 0u);
      bef[q] = mk2(g==0 ? pkbf(di[q], zz[q]) : 0u, g==0 ? pkbf(sp[q], 0.f) : 0u);
    }

    // ---- embeddings ----
    f4v t0[4], t1[4], te[4], h0[4], h1[4], ee[4];
    { s4v A = ld8(0); f4v C = ldc(0);
      #pragma unroll
      for (int q = 0; q < 4; ++q){ t0[q] = MM16(A, b0f[q], C); t1[q] = MM16(A, b1f[q], C); } }
    { s4v A = ld8(2); f4v C = ldc(2);
      #pragma unroll
      for (int q = 0; q < 4; ++q){ te[q] = MM16(A, bef[q], C); } }
    { s4v A = ld8(1); f4v C = ldc(1);
      #pragma unroll
      for (int q = 0; q < 4; ++q){
        h0[q] = MM16(A, pk2b(mkpk<true>(t0[q])), C);
        h1[q] = MM16(A, pk2b(mkpk<true>(t1[q])), C); } }
    s4v eeB[4];
    { s4v A = ld8(3); f4v C = ldc(3);
      #pragma unroll
      for (int q = 0; q < 4; ++q){ ee[q] = MM16(A, pk2b(mkpk<true>(te[q])), C); } }
    #pragma unroll
    for (int q = 0; q < 4; ++q){ eeB[q] = pk2b(mkpk<false>(ee[q])); }

    // ---- eC HOIST (R17, proven): off the h-dependent critical chain ----
    f4v eC[2][4];
    #pragma unroll
    for (int l = 0; l < 2; ++l){
      s4v A = ld8(5+l); f4v C = ldc(5+l);
      #pragma unroll
      for (int q = 0; q < 4; ++q){ eC[l][q] = MM16(A, eeB[q], C); }
    }

    // ---- message-passing layers (K=32 = two chained MM16: hi·y + (lo·x + C)) ----
    #pragma unroll
    for (int l = 0; l < 2; ++l){
      s4v ph0[4], ph1[4];
      #pragma unroll
      for (int q = 0; q < 4; ++q){ ph0[q] = pk2b(mkpk<false>(h0[q])); ph1[q] = pk2b(mkpk<false>(h1[q])); }
      f4v m0[4], m1[4];
      { A32 A = ld16(l);
        #pragma unroll
        for (int q = 0; q < 4; ++q){
          m0[q] = MM16(A.hi, ph1[q], MM16(A.lo, ph0[q], eC[l][q]));
          m1[q] = MM16(A.hi, ph0[q], MM16(A.lo, ph1[q], eC[l][q])); } }
      f4v g0[4], g1[4];
      { s4v A = ld8(7+l); f4v C = ldc(7+l);
        #pragma unroll
        for (int q = 0; q < 4; ++q){
          g0[q] = MM16(A, pk2b(mkpk<true>(m0[q])), C);
          g1[q] = MM16(A, pk2b(mkpk<true>(m1[q])), C); } }
      f4v u0[4], u1[4];
      { A32 A = ld16(2+l); f4v C = ldc(9+l);
        #pragma unroll
        for (int q = 0; q < 4; ++q){
          u0[q] = MM16(A.hi, pk2b(mkpk<false>(g0[q])), MM16(A.lo, ph0[q], C));
          u1[q] = MM16(A.hi, pk2b(mkpk<false>(g1[q])), MM16(A.lo, ph1[q], C)); } }
      { s4v A = ld8(9+l); f4v C = ldc(11+l);
        #pragma unroll
        for (int q = 0; q < 4; ++q){
          h0[q] = h0[q] + MM16(A, pk2b(mkpk<true>(u0[q])), C);
          h1[q] = h1[q] + MM16(A, pk2b(mkpk<true>(u1[q])), C); } }
    }

    // ---- classifier (0.5 pre-folded into the aCl fragment) ----
    { s4v A = ld8(4); f4v C = ldc(4); f4v w2v = ldc(13);
      #pragma unroll
      for (int q = 0; q < 4; ++q){
        f4v tc = MM16(A, pk2b(mkpk<false>(h0[q] + h1[q])), C);
        float part = fmaxf(tc[0],0.f)*w2v[0] + fmaxf(tc[1],0.f)*w2v[1]
                   + fmaxf(tc[2],0.f)*w2v[2] + fmaxf(tc[3],0.f)*w2v[3];
        part = qsum(part);
        int e = (4*it + q)*16 + c;
        if (lane < 16 && e < B) out[e] = part + cb2;
      } }

    #pragma unroll
    for (int q = 0; q < 4; ++q){ nfe[q] = nfeN[q]; di[q]=diN[q]; zz[q]=zzN[q]; sp[q]=spN[q]; }
  }
}

extern "C" void kernel_launch(void* const* d_in, const int* in_sizes, int n_in,
                              void* d_out, int out_size, void* d_ws, size_t ws_size,
                              hipStream_t stream) {
  const float* nf    = (const float*)d_in[0];
  const float* dist  = (const float*)d_in[1];
  const float* dz    = (const float*)d_in[2];
  const float* s2p   = (const float*)d_in[3];
  const float* neW1  = (const float*)d_in[4];
  const float* neb1  = (const float*)d_in[5];
  const float* neW2  = (const float*)d_in[6];
  const float* neb2  = (const float*)d_in[7];
  const float* eeW1  = (const float*)d_in[8];
  const float* eeb1  = (const float*)d_in[9];
  const float* eeW2  = (const float*)d_in[10];
  const float* eeb2  = (const float*)d_in[11];
  const float* msgW1 = (const float*)d_in[12];
  const float* msgb1 = (const float*)d_in[13];
  const float* msgW2 = (const float*)d_in[14];
  const float* msgb2 = (const float*)d_in[15];
  const float* updW1 = (const float*)d_in[16];
  const float* updb1 = (const float*)d_in[17];
  const float* updW2 = (const float*)d_in[18];
  const float* updb2 = (const float*)d_in[19];
  const float* clsW1 = (const float*)d_in[20];
  const float* clsb1 = (const float*)d_in[21];
  const float* clsW2 = (const float*)d_in[22];
  const float* clsb2 = (const float*)d_in[23];

  const int B = in_sizes[1];
  const int ngroups = (B + 15) / 16;
  const int niters  = (ngroups + 3) / 4;       // 4 groups per wave-iteration
  // R17's proven-best config: 1024 blocks (4 iters/wave).
  int blocks = 1024;
  if (blocks * 4 > niters) blocks = (niters + 3) / 4;
  const int nwaves = blocks * 4;

  egnn_m16<<<blocks, 256, 0, stream>>>(
      nf, dist, dz, s2p,
      neW1, neb1, neW2, neb2,
      eeW1, eeb1, eeW2, eeb2,
      msgW1, msgb1, msgW2, msgb2,
      updW1, updb1, updW2, updb2,
      clsW1, clsb1, clsW2, clsb2,
      (float*)d_out, B, niters, nwaves);
}